// Round 8
// baseline (58.421 us; speedup 1.0000x reference)
//
#include <hip/hip_runtime.h>

// Triplet generation (DimeNet-style) for constant-degree graph.
// Outputs (concatenated in d_out as float32): id3_i, id3_j, id3_k,
// distances_jk, angles, mask — each num_nodes*DEG*DEG elements.
//
// R8: wave-per-stream epilogue. Phase 2 deposits dist/ang in LDS; phase 3
// assigns one output array per wave, so each wave writes ONE contiguous
// 8KB stream (8 x 1KB coalesced dwordx4 stores) instead of interleaving
// 6 streams 51.2MB apart. Tests whether per-wave multi-stream store
// interleave is what costs us vs pure-fill bandwidth.

#define DEG 16
#define NODES_PER_BLOCK 8
#define THREADS (NODES_PER_BLOCK * 64)
#define CUTOFF_F 5.0f

typedef float f32x4 __attribute__((ext_vector_type(4)));

// fast atan2 for y >= 0: result in [0, pi]; atan2(0, 0) -> 0 (matches numpy).
__device__ __forceinline__ float fast_atan2_pos(float y, float x) {
    const float PI_F   = 3.14159274f;
    const float PIO2_F = 1.57079637f;
    const float ax = fabsf(x);
    const float mn = fminf(ax, y);
    const float mx = fmaxf(ax, y);
    const float a = (mx > 0.0f) ? __fdividef(mn, mx) : 0.0f;
    const float s = a * a;
    float r = fmaf(s, fmaf(s, fmaf(s, fmaf(s, 0.0208351f, -0.085133f),
                                   0.180141f), -0.3302995f), 0.9998660f);
    r *= a;
    if (y > ax)    r = PIO2_F - r;
    if (x < 0.0f)  r = PI_F - r;
    return r;
}

__global__ __launch_bounds__(THREADS) void triplet_kernel(
    const float* __restrict__ pos,       // [N,3]
    const int* __restrict__ col_idx,     // edge_index[1], length N*DEG
    float* __restrict__ out,             // f32, 6 arrays of P each
    int num_nodes, int P)
{
    __shared__ float sx[128], sy[128], sz[128], scolf[128];
    __shared__ int   sval[128];
    __shared__ float sdist[NODES_PER_BLOCK * 256];   // 8KB
    __shared__ float sang[NODES_PER_BLOCK * 256];    // 8KB

    const int base = blockIdx.x * NODES_PER_BLOCK;
    const int tid = threadIdx.x;

    // Phase 1: first 128 threads stage R1 vectors, validity, neighbor ids.
    if (tid < NODES_PER_BLOCK * DEG) {
        int nl = tid >> 4;
        int slot = tid & 15;
        int node = base + nl;
        if (node < num_nodes) {
            int c = col_idx[node * DEG + slot];
            float px = pos[3 * node], py = pos[3 * node + 1], pz = pos[3 * node + 2];
            float rx = pos[3 * c]     - px;
            float ry = pos[3 * c + 1] - py;
            float rz = pos[3 * c + 2] - pz;
            float d = sqrtf(rx * rx + ry * ry + rz * rz);
            sx[tid] = rx; sy[tid] = ry; sz[tid] = rz;
            scolf[tid] = (float)c;
            sval[tid] = (d <= CUTOFF_F) ? 1 : 0;
        }
    }
    __syncthreads();

    // Phase 2: wave w computes node base+w's 256 pairs; deposit dist/ang in LDS.
    const int w = tid >> 6;
    const int lane = tid & 63;
    {
        const int node = base + w;
        if (node < num_nodes) {
            const int ofs = w * DEG;
            const int j = lane >> 2;
            const int k0 = (lane & 3) << 2;

            const float jx = sx[ofs + j], jy = sy[ofs + j], jz = sz[ofs + j];
            const int   jv = sval[ofs + j];

            f32x4 o_d, o_a;

            #pragma unroll
            for (int q = 0; q < 4; ++q) {
                const int k = k0 + q;
                const float kx = sx[ofs + k], ky = sy[ofs + k], kz = sz[ofs + k];
                const int   kv = sval[ofs + k];
                const bool m = (jv != 0) && (kv != 0) && (j != k);

                const float dot = jx * kx + jy * ky + jz * kz;
                const float cx = jy * kz - jz * ky;
                const float cy = jz * kx - jx * kz;
                const float cz = jx * ky - jy * kx;
                const float cn2 = cx * cx + cy * cy + cz * cz;
                const float ang = m ? fast_atan2_pos(sqrtf(cn2), dot) : 0.0f;

                const float dx = jx - kx, dy = jy - ky, dz = jz - kz;
                const float d2 = dx * dx + dy * dy + dz * dz;
                const float dist = m ? sqrtf(d2 > 0.0f ? d2 : 1.0f) : 0.0f;

                o_d[q] = dist;
                o_a[q] = ang;
            }
            // pair-base for this lane is 16*(lane>>2)+4*(lane&3) == 4*lane:
            // perfectly linear b128 writes.
            *reinterpret_cast<f32x4*>(&sdist[w * 256 + 4 * lane]) = o_d;
            *reinterpret_cast<f32x4*>(&sang[w * 256 + 4 * lane])  = o_a;
        }
    }
    __syncthreads();

    // Phase 3: wave w (< 6) writes output array w's whole block-span (8KB)
    // as one contiguous stream of 8 coalesced 1KB stores.
    if (w < 6) {
        float* const arr = out + w * P;
        #pragma unroll
        for (int c = 0; c < NODES_PER_BLOCK; ++c) {
            const int node = base + c;
            if (node >= num_nodes) break;
            const int g = node * 256 + 4 * lane;
            f32x4 v;
            if (w == 0) {
                const float fv = (float)node;
                v[0] = fv; v[1] = fv; v[2] = fv; v[3] = fv;
            } else if (w == 1) {
                const float jv = scolf[c * 16 + (lane >> 2)];
                v[0] = jv; v[1] = jv; v[2] = jv; v[3] = jv;
            } else if (w == 2) {
                v = *reinterpret_cast<const f32x4*>(&scolf[c * 16 + 4 * (lane & 3)]);
            } else if (w == 3) {
                v = *reinterpret_cast<const f32x4*>(&sdist[c * 256 + 4 * lane]);
            } else if (w == 4) {
                v = *reinterpret_cast<const f32x4*>(&sang[c * 256 + 4 * lane]);
            } else {
                const f32x4 d = *reinterpret_cast<const f32x4*>(&sdist[c * 256 + 4 * lane]);
                v[0] = d[0] > 0.0f ? 1.0f : 0.0f;
                v[1] = d[1] > 0.0f ? 1.0f : 0.0f;
                v[2] = d[2] > 0.0f ? 1.0f : 0.0f;
                v[3] = d[3] > 0.0f ? 1.0f : 0.0f;
            }
            *reinterpret_cast<f32x4*>(arr + g) = v;
        }
    }
}

extern "C" void kernel_launch(void* const* d_in, const int* in_sizes, int n_in,
                              void* d_out, int out_size, void* d_ws, size_t ws_size,
                              hipStream_t stream) {
    const float* pos = (const float*)d_in[0];
    const int* edge_index = (const int*)d_in[1];

    const int num_nodes = in_sizes[0] / 3;
    const int E = in_sizes[1] / 2;          // edge_index is [2, E]
    const int* col = edge_index + E;        // row 1 = neighbor ids

    const int P = num_nodes * (DEG * DEG);  // 12.8M, int-safe
    const int blocks = (num_nodes + NODES_PER_BLOCK - 1) / NODES_PER_BLOCK;

    triplet_kernel<<<blocks, THREADS, 0, stream>>>(
        pos, col, (float*)d_out, num_nodes, P);
}

// Round 9
// 53.337 us; speedup vs baseline: 1.0953x; 1.0953x over previous
//
#include <hip/hip_runtime.h>

// Triplet generation (DimeNet-style) for constant-degree graph.
// Outputs (concatenated in d_out as float32): id3_i, id3_j, id3_k,
// distances_jk, angles, mask — each num_nodes*DEG*DEG elements.
//
// R9: identical structure to R7 (direct 6-stream stores, one barrier),
// NODES_PER_BLOCK 8 -> 16 (1024 threads, 3125 workgroups) to test
// whether workgroup dispatch/ramp overhead is the residual ~9us.

#define DEG 16
#define NODES_PER_BLOCK 16
#define THREADS (NODES_PER_BLOCK * 64)
#define CUTOFF_F 5.0f

typedef float f32x4 __attribute__((ext_vector_type(4)));

// fast atan2 for y >= 0: result in [0, pi]; atan2(0, 0) -> 0 (matches numpy).
__device__ __forceinline__ float fast_atan2_pos(float y, float x) {
    const float PI_F   = 3.14159274f;
    const float PIO2_F = 1.57079637f;
    const float ax = fabsf(x);
    const float mn = fminf(ax, y);
    const float mx = fmaxf(ax, y);
    const float a = (mx > 0.0f) ? __fdividef(mn, mx) : 0.0f;
    const float s = a * a;
    float r = fmaf(s, fmaf(s, fmaf(s, fmaf(s, 0.0208351f, -0.085133f),
                                   0.180141f), -0.3302995f), 0.9998660f);
    r *= a;
    if (y > ax)    r = PIO2_F - r;
    if (x < 0.0f)  r = PI_F - r;
    return r;
}

__global__ __launch_bounds__(THREADS) void triplet_kernel(
    const float* __restrict__ pos,       // [N,3]
    const int* __restrict__ col_idx,     // edge_index[1], length N*DEG
    float* __restrict__ out,             // f32, 6 arrays of P each
    int num_nodes, int P)
{
    // NODES_PER_BLOCK nodes * 16 neighbors
    __shared__ float sx[THREADS / 4], sy[THREADS / 4], sz[THREADS / 4];
    __shared__ float scolf[THREADS / 4];
    __shared__ int   sval[THREADS / 4];

    const int base = blockIdx.x * NODES_PER_BLOCK;
    const int tid = threadIdx.x;

    // Phase 1: first NODES_PER_BLOCK*16 threads stage R1, validity, ids.
    if (tid < NODES_PER_BLOCK * DEG) {
        int nl = tid >> 4;           // local node
        int slot = tid & 15;         // neighbor slot
        int node = base + nl;
        if (node < num_nodes) {
            int c = col_idx[node * DEG + slot];
            float px = pos[3 * node], py = pos[3 * node + 1], pz = pos[3 * node + 2];
            float rx = pos[3 * c]     - px;
            float ry = pos[3 * c + 1] - py;
            float rz = pos[3 * c + 2] - pz;
            float d = sqrtf(rx * rx + ry * ry + rz * rz);
            sx[tid] = rx; sy[tid] = ry; sz[tid] = rz;
            scolf[tid] = (float)c;
            sval[tid] = (d <= CUTOFF_F) ? 1 : 0;
        }
    }
    __syncthreads();

    // Phase 2: wave w handles node base+w; lane handles 4 consecutive pairs
    // (fixed j = lane>>2, k in [k0, k0+4)) -> flat index 4*lane + q.
    const int w = tid >> 6;
    const int lane = tid & 63;
    const int node = base + w;
    if (node >= num_nodes) return;

    const int ofs = w * DEG;
    const int j = lane >> 2;
    const int k0 = (lane & 3) << 2;

    const float jx = sx[ofs + j], jy = sy[ofs + j], jz = sz[ofs + j];
    const int   jv = sval[ofs + j];
    const float jcolf = scolf[ofs + j];

    f32x4 o_k, o_d, o_a, o_m;

    #pragma unroll
    for (int q = 0; q < 4; ++q) {
        const int k = k0 + q;
        const float kx = sx[ofs + k], ky = sy[ofs + k], kz = sz[ofs + k];
        const int   kv = sval[ofs + k];
        const bool m = (jv != 0) && (kv != 0) && (j != k);

        // angle(j,i,k) = atan2(|R1_j x R1_k|, R1_j . R1_k)
        const float dot = jx * kx + jy * ky + jz * kz;
        const float cx = jy * kz - jz * ky;
        const float cy = jz * kx - jx * kz;
        const float cz = jx * ky - jy * kx;
        const float cn2 = cx * cx + cy * cy + cz * cz;
        const float ang = m ? fast_atan2_pos(sqrtf(cn2), dot) : 0.0f;

        // |R1_j - R1_k| with the reference's d2==0 -> 1.0 quirk
        const float dx = jx - kx, dy = jy - ky, dz = jz - kz;
        const float d2 = dx * dx + dy * dy + dz * dz;
        const float dist = m ? sqrtf(d2 > 0.0f ? d2 : 1.0f) : 0.0f;

        o_k[q] = scolf[ofs + k];
        o_d[q] = dist;
        o_a[q] = ang;
        o_m[q] = m ? 1.0f : 0.0f;
    }

    const int idx = node * (DEG * DEG) + lane * 4;   // < 12.8M, int-safe
    const float fi = (float)node;
    f32x4 o_i; o_i[0] = fi; o_i[1] = fi; o_i[2] = fi; o_i[3] = fi;
    f32x4 o_j; o_j[0] = jcolf; o_j[1] = jcolf; o_j[2] = jcolf; o_j[3] = jcolf;

    float* o0 = out + idx;
    *reinterpret_cast<f32x4*>(o0)         = o_i;
    *reinterpret_cast<f32x4*>(o0 + P)     = o_j;
    *reinterpret_cast<f32x4*>(o0 + 2 * P) = o_k;
    *reinterpret_cast<f32x4*>(o0 + 3 * P) = o_d;
    *reinterpret_cast<f32x4*>(o0 + 4 * P) = o_a;
    *reinterpret_cast<f32x4*>(o0 + 5 * P) = o_m;
}

extern "C" void kernel_launch(void* const* d_in, const int* in_sizes, int n_in,
                              void* d_out, int out_size, void* d_ws, size_t ws_size,
                              hipStream_t stream) {
    const float* pos = (const float*)d_in[0];
    const int* edge_index = (const int*)d_in[1];

    const int num_nodes = in_sizes[0] / 3;
    const int E = in_sizes[1] / 2;          // edge_index is [2, E]
    const int* col = edge_index + E;        // row 1 = neighbor ids

    const int P = num_nodes * (DEG * DEG);  // 12.8M, int-safe
    const int blocks = (num_nodes + NODES_PER_BLOCK - 1) / NODES_PER_BLOCK;

    triplet_kernel<<<blocks, THREADS, 0, stream>>>(
        pos, col, (float*)d_out, num_nodes, P);
}